// Round 8
// baseline (377.555 us; speedup 1.0000x reference)
//
#include <hip/hip_runtime.h>
#include <cfloat>
#include <climits>

#define T_TOKENS 65536
#define K_EMB 4096
#define D_DIM 256
#define QOFF ((size_t)T_TOKENS * D_DIM)   // 16777216
#define WINDOW 1.2e-4f                     // rescue window in biased-score units
#define B0 0.03125f                        // positivity bias baked into acc init
#define KSPLIT 4
#define KCHUNK (K_EMB / KSPLIT)            // 1024 codes per k-split
#define NTILES (KCHUNK / 32)               // 32 tiles per block

using bf16x8 = __attribute__((ext_vector_type(8))) short;
using f32x16 = __attribute__((ext_vector_type(16))) float;

// fp32 multiply, contraction into later add blocked (numpy rounds the square first)
__device__ __forceinline__ float fmul_nc(float a, float b) {
    float c = a * b;
    asm volatile("" : "+v"(c));
    return c;
}

__device__ __forceinline__ double wave_sum_d(double v) {
#pragma unroll
    for (int o = 32; o >= 1; o >>= 1) v += __shfl_down(v, o, 64);
    return v;
}

// async global->LDS DMA, 16B per lane; lds base must be wave-uniform.
__device__ __forceinline__ void glds16(const void* g, void* l) {
    __builtin_amdgcn_global_load_lds((const __attribute__((address_space(1))) void*)g,
                                     (__attribute__((address_space(3))) void*)l, 16, 0, 0);
}

// round-to-nearest-even fp32 -> bf16 bits
__device__ __forceinline__ unsigned short f2bf(float f) {
    unsigned u = __float_as_uint(f);
    u += 0x7FFFu + ((u >> 16) & 1u);
    return (unsigned short)(u >> 16);
}

// Fused emb pass: C32[k] = fp32(||e_k||^2) (validated double wave-sum) and
// bf16-hi split store. One block per code row.
__global__ __launch_bounds__(256)
void emb_prep_kernel(const float* __restrict__ emb, float* __restrict__ c32,
                     unsigned short* __restrict__ ehi) {
    const int k = blockIdx.x;
    const float e = emb[(size_t)k * D_DIM + threadIdx.x];
    ehi[(size_t)k * D_DIM + threadIdx.x] = f2bf(e);
    const double v = (double)e;
    double s = wave_sum_d(v * v);
    __shared__ double wsm[4];
    const int lane = threadIdx.x & 63, w = threadIdx.x >> 6;
    if (lane == 0) wsm[w] = s;
    __syncthreads();
    if (threadIdx.x == 0) c32[k] = (float)(wsm[0] + wsm[1] + wsm[2] + wsm[3]);
}

// MFMA candidate filter v8: v7's 2-token-set B-reuse structure (each e-tile
// ds_read feeds two mfmas) + k-split x4 to restore TLP (v7 collapsed to ~1
// wave/SIMD and serialized; 1024 blocks -> 3 resident/CU -> dep-chains and
// barriers hidden). Block = 256 tokens x 1024 codes (32 tiles). e-hi LDS
// dbuf 32 KB, both-sides XOR swizzle. Scores biased by B0 via acc init ->
// positive -> float bits monotone as u32 -> pack code id in low 12 bits ->
// top-4 per (k-quarter, lane-half) via pure v_max/min_u32 chain. Exact
// argmin recovered by rescoring keys within WINDOW with the validated chain.
__global__ __launch_bounds__(256)
void argmin_mfma_kernel(const float* __restrict__ z,
                        const unsigned short* __restrict__ ehi,
                        unsigned int* __restrict__ keyout)
{
    __shared__ short lds_e[2][32 * 256];   // 2 x 16 KiB

    const int tid = threadIdx.x;
    const int wv  = tid >> 6;
    const int l   = tid & 63;
    const int lr  = l & 31;          // A-row (code) / D-col (token) lane index
    const int h   = l >> 5;          // k-half within the mfma fragment
    const int tokA = blockIdx.x * 256 + wv * 64 + lr;
    const int tokB = tokA + 32;
    const int kbase = blockIdx.y * KCHUNK;

    // z fragments for both token sets, bf16 hi only
    bf16x8 zA[16], zB[16];
#pragma unroll
    for (int st = 0; st < 16; st++) {
        {
            const float* zp = z + (size_t)tokA * D_DIM + st * 16 + h * 8;
            const float4 f0 = *(const float4*)zp;
            const float4 f1 = *(const float4*)(zp + 4);
            const float f[8] = {f0.x, f0.y, f0.z, f0.w, f1.x, f1.y, f1.z, f1.w};
#pragma unroll
            for (int j = 0; j < 8; j++) zA[st][j] = (short)f2bf(f[j]);
        }
        {
            const float* zp = z + (size_t)tokB * D_DIM + st * 16 + h * 8;
            const float4 f0 = *(const float4*)zp;
            const float4 f1 = *(const float4*)(zp + 4);
            const float f[8] = {f0.x, f0.y, f0.z, f0.w, f1.x, f1.y, f1.z, f1.w};
#pragma unroll
            for (int j = 0; j < 8; j++) zB[st][j] = (short)f2bf(f[j]);
        }
    }

    unsigned a1 = 0u, a2 = 0u, a3 = 0u, a4 = 0u;   // set-A top-4 keys
    unsigned c1 = 0u, c2 = 0u, c3 = 0u, c4 = 0u;   // set-B top-4 keys

    // stage tile ct: 16 glds16 (4/wave), 2 rows per request; source chunk
    // pre-swizzled g = lr^(r&7) so linear LDS dest + swizzled read match.
    // r&7 = 2q|h  (since (wv*4+q)&3 == q).
    auto stage = [&](int buf, int ct) {
#pragma unroll
        for (int q = 0; q < 4; q++) {
            const int rp = wv * 4 + q;
            const int r  = 2 * rp + h;
            const int g  = lr ^ ((2 * q) | h);
            const unsigned short* src =
                ehi + (size_t)(kbase + ct * 32 + r) * D_DIM + g * 8;
            glds16(src, &lds_e[buf][rp * 512]);
        }
    };

    stage(0, 0);
    __syncthreads();

    const int lk = lr & 7;
    const short* lrow0 = &lds_e[0][lr * 256];
    const short* lrow1 = &lds_e[1][lr * 256];
    const unsigned vh4 = (unsigned)(4 * h);

    int buf = 0;
    for (int ct = 0; ct < NTILES; ct++) {
        if (ct + 1 < NTILES) stage(buf ^ 1, ct + 1);

        f32x16 pA, pB;
#pragma unroll
        for (int i = 0; i < 16; i++) { pA[i] = B0; pB[i] = B0; }   // bias free

        const short* lrow = buf ? lrow1 : lrow0;
#pragma unroll
        for (int st = 0; st < 16; st++) {
            const bf16x8 eh = *(const bf16x8*)(lrow + (((2 * st + h) ^ lk) << 3));
            pA = __builtin_amdgcn_mfma_f32_32x32x16_bf16(eh, zA[st], pA, 0, 0, 0);
            pB = __builtin_amdgcn_mfma_f32_32x32x16_bf16(eh, zB[st], pB, 0, 0, 0);
        }

        // epilogue: pack biased score + code id, keep top-4 (max/min chain)
        const unsigned korb = (unsigned)(kbase + ct * 32) | vh4;
#pragma unroll
        for (int r = 0; r < 16; r++) {
            const unsigned rid = korb | (unsigned)((r & 3) + 8 * (r >> 2));
            unsigned t = (__float_as_uint(pA[r]) & 0xFFFFF000u) | rid;
            {
                const unsigned n1 = a1 > t ? a1 : t; t = a1 > t ? t : a1; a1 = n1;
                const unsigned n2 = a2 > t ? a2 : t; t = a2 > t ? t : a2; a2 = n2;
                const unsigned n3 = a3 > t ? a3 : t; t = a3 > t ? t : a3; a3 = n3;
                a4 = a4 > t ? a4 : t;
            }
            unsigned u = (__float_as_uint(pB[r]) & 0xFFFFF000u) | rid;
            {
                const unsigned n1 = c1 > u ? c1 : u; u = c1 > u ? u : c1; c1 = n1;
                const unsigned n2 = c2 > u ? c2 : u; u = c2 > u ? u : c2; c2 = n2;
                const unsigned n3 = c3 > u ? c3 : u; u = c3 > u ? u : c3; c3 = n3;
                c4 = c4 > u ? c4 : u;
            }
        }
        __syncthreads();   // readers of buf done; DMA into buf^1 drained
        buf ^= 1;
    }

    // coalesced: per token 8 dwords (h=0 then h=1), k-splits stacked by T.
    *(uint4*)(keyout + (((size_t)blockIdx.y * T_TOKENS + tokA) << 3) + vh4) =
        make_uint4(a1, a2, a3, a4);
    *(uint4*)(keyout + (((size_t)blockIdx.y * T_TOKENS + tokB) << 3) + vh4) =
        make_uint4(c1, c2, c3, c4);
}

// Rescore v8: a32 in-place (validated round-4 pairwise chain, bit-identical),
// 4 threads/token (one k-quarter each, 8 keys), tie-rule combine; gather
// parallelized per-wave: wave w owns 16 tokens, lane l covers dims 4l..4l+3
// with float4 emb/out accesses (replaces v7's 64-serial-iteration broadcast).
__global__ __launch_bounds__(256)
void rescore_gather_kernel(const float* __restrict__ z, const float* __restrict__ emb,
                           const float* __restrict__ c32,
                           const unsigned int* __restrict__ keyout,
                           float* __restrict__ out, double* __restrict__ partials)
{
    __shared__ float zt[64][257];
    __shared__ float a32sm[64];
    __shared__ unsigned lmax[4][64];
    __shared__ float bvq[4][64];
    __shared__ int bkq[4][64];
    __shared__ int win[64];
    __shared__ double lsm[4];
    const int tid = threadIdx.x;
    const int base = blockIdx.x * 64;

    for (int idx = tid; idx < 64 * 256; idx += 256) {
        const int r = idx >> 8, c = idx & 255;
        zt[r][c] = z[(size_t)(base + r) * D_DIM + c];
    }
    __syncthreads();

    // A32[t]: np.float32 pairwise sum of z[t]**2 (validated round-4 chain)
    if (tid < 64) {
        const float* row = zt[tid];
        float S[2];
        for (int hh = 0; hh < 2; hh++) {
            const float* p = row + hh * 128;
            float r[8];
#pragma unroll
            for (int j = 0; j < 8; j++) r[j] = fmul_nc(p[j], p[j]);
            for (int m = 1; m < 16; m++) {
#pragma unroll
                for (int j = 0; j < 8; j++) r[j] += fmul_nc(p[8 * m + j], p[8 * m + j]);
            }
            S[hh] = ((r[0] + r[1]) + (r[2] + r[3])) + ((r[4] + r[5]) + (r[6] + r[7]));
        }
        a32sm[tid] = S[0] + S[1];
    }

    // per-quarter keys: qq = k-split quarter, both lane-halves (8 keys)
    const int ti = tid & 63, qq = tid >> 6;
    const int t = base + ti;
    const uint4 k0 = *(const uint4*)(keyout + (((size_t)qq * T_TOKENS + t) << 3));
    const uint4 k1 = *(const uint4*)(keyout + (((size_t)qq * T_TOKENS + t) << 3) + 4);
    const unsigned ks[8] = {k0.x, k0.y, k0.z, k0.w, k1.x, k1.y, k1.z, k1.w};
    unsigned lm = 0u;
#pragma unroll
    for (int s = 0; s < 8; s++) lm = lm > ks[s] ? lm : ks[s];
    lmax[qq][ti] = lm;
    __syncthreads();

    unsigned gm = lmax[0][ti];
#pragma unroll
    for (int e = 1; e < 4; e++) gm = gm > lmax[e][ti] ? gm : lmax[e][ti];
    const float thr = __uint_as_float(gm) - WINDOW;
    const float ar = a32sm[ti];
    float bestv = FLT_MAX; int bestk = INT_MAX;
#pragma unroll
    for (int s = 0; s < 8; s++) {
        if (__uint_as_float(ks[s]) >= thr) {
            const int k = (int)(ks[s] & 0xFFFu);
            const float* er = emb + (size_t)k * D_DIM;
            float m = 0.0f;
#pragma unroll 8
            for (int d4 = 0; d4 < 64; d4++) {
                const float4 e4 = *(const float4*)(er + 4 * d4);
                m = fmaf(zt[ti][4 * d4 + 0], e4.x, m);
                m = fmaf(zt[ti][4 * d4 + 1], e4.y, m);
                m = fmaf(zt[ti][4 * d4 + 2], e4.z, m);
                m = fmaf(zt[ti][4 * d4 + 3], e4.w, m);
            }
            const float v1 = ar - 2.0f * m;
            const float v2 = v1 + c32[k];
            if (v2 < bestv || (v2 == bestv && k < bestk)) { bestv = v2; bestk = k; }
        }
    }
    bvq[qq][ti] = bestv; bkq[qq][ti] = bestk;
    __syncthreads();

    if (tid < 64) {
        float B = bvq[0][tid];
        int I = bkq[0][tid];
#pragma unroll
        for (int e = 1; e < 4; e++) {
            const float cv = bvq[e][tid];
            const int ck = bkq[e][tid];
            if (cv < B || (cv == B && ck < I)) { B = cv; I = ck; }
        }
        win[tid] = I;
    }
    __syncthreads();

    // gather: wave w owns tokens base+16w..+15; lane covers dims 4l..4l+3
    const int lane = tid & 63, w = tid >> 6;
    double lacc = 0.0;
#pragma unroll 4
    for (int s = 0; s < 16; s++) {
        const int ti2 = w * 16 + s;
        const int sel = win[ti2];
        const float4 e4 = *(const float4*)(emb + (size_t)sel * D_DIM + 4 * lane);
        const float z0 = zt[ti2][4 * lane + 0], z1 = zt[ti2][4 * lane + 1];
        const float z2 = zt[ti2][4 * lane + 2], z3 = zt[ti2][4 * lane + 3];
        *(float4*)(out + (size_t)(base + ti2) * D_DIM + 4 * lane) = e4;
        if (lane == 0) out[QOFF + base + ti2] = (float)sel;
        const double d0 = (double)z0 - (double)e4.x;
        const double d1 = (double)z1 - (double)e4.y;
        const double d2 = (double)z2 - (double)e4.z;
        const double d3 = (double)z3 - (double)e4.w;
        lacc += d0 * d0 + d1 * d1 + d2 * d2 + d3 * d3;
    }
    lacc = wave_sum_d(lacc);
    if (lane == 0) lsm[w] = lacc;
    __syncthreads();
    if (tid == 0) partials[blockIdx.x] = lsm[0] + lsm[1] + lsm[2] + lsm[3];
}

__global__ void finalize_kernel(const double* __restrict__ partials, float* __restrict__ out) {
    __shared__ double rsm[4];
    const int tid = threadIdx.x;
    double s = 0.0;
    for (int i = tid; i < 1024; i += 256) s += partials[i];
    s = wave_sum_d(s);
    if ((tid & 63) == 0) rsm[tid >> 6] = s;
    __syncthreads();
    if (tid == 0) {
        const double mean = (rsm[0] + rsm[1] + rsm[2] + rsm[3]) / (double)QOFF;
        out[QOFF + T_TOKENS] = (float)(1.25 * mean);
    }
}

extern "C" void kernel_launch(void* const* d_in, const int* in_sizes, int n_in,
                              void* d_out, int out_size, void* d_ws, size_t ws_size,
                              hipStream_t stream)
{
    const float* z = (const float*)d_in[0];
    const float* emb = (const float*)d_in[1];
    float* out = (float*)d_out;
    char* ws = (char*)d_ws;

    float* c32 = (float*)ws;                                  // 16384 B
    unsigned int* keyout = (unsigned int*)(ws + 16384);       // 4*65536*8*4 = 8388608 B
    unsigned short* ehi = (unsigned short*)(ws + 8404992);    // 2097152 B
    double* partials = (double*)(ws + 10502144);              // 8192 B

    emb_prep_kernel<<<K_EMB, 256, 0, stream>>>(emb, c32, ehi);
    argmin_mfma_kernel<<<dim3(T_TOKENS / 256, KSPLIT), 256, 0, stream>>>(z, ehi, keyout);
    rescore_gather_kernel<<<T_TOKENS / 64, 256, 0, stream>>>(z, emb, c32, keyout, out, partials);
    finalize_kernel<<<1, 256, 0, stream>>>(partials, out);
}